// Round 1
// baseline (1103.598 us; speedup 1.0000x reference)
//
#include <hip/hip_runtime.h>

#define NROWS  131072
#define ND     13
#define NS     26
#define NF     39
#define EMBD   16
#define DDIM   624      // 39*16
#define HIDN   32
#define VOCABN 100000
#define EPSF   1e-5f

// ---------------------------------------------------------------------------
// K1: per 16-row block:
//   - gather both embedding tables (coalesced: 16 lanes = one 64B line/field)
//   - base[n] = first.sum + fm2.sum + bias          (FM part, closed per-row)
//   - deep (second emb, 624 floats/row) staged in LDS
//   - y1[n,:] = deep @ Wl1 + bl1  (fused, float2-vectorized Wl1 loads)
//   - atomic block-partial column sums / sumsq of y1 (BN1 statistics)
// ---------------------------------------------------------------------------
__global__ __launch_bounds__(256) void k1_embed(
    const float* __restrict__ Xi_dense, const int* __restrict__ Xi_sparse,
    const float* __restrict__ Xv, const float* __restrict__ bias,
    const float* __restrict__ W1d, const float* __restrict__ b1d,
    const float* __restrict__ T1,
    const float* __restrict__ W2d, const float* __restrict__ b2d,
    const float* __restrict__ T2,
    const float* __restrict__ Wl1, const float* __restrict__ bl1,
    float* __restrict__ base, float* __restrict__ y1,
    float* __restrict__ S1, float* __restrict__ Q1)
{
    __shared__ float deep_s[16 * DDIM];   // 39.9 KB
    __shared__ float xv_s[16 * NF];
    __shared__ int   xs_s[16 * NS];
    __shared__ float xd_s[16 * ND];
    __shared__ float s1_s[HIDN];
    __shared__ float q1_s[HIDN];

    const int t  = threadIdx.x;
    const int n0 = blockIdx.x * 16;

    // stage per-row scalars (rows are contiguous in global memory)
    for (int i = t; i < 16 * NF; i += 256) xv_s[i] = Xv[n0 * NF + i];
    for (int i = t; i < 16 * NS; i += 256) xs_s[i] = Xi_sparse[n0 * NS + i];
    for (int i = t; i < 16 * ND; i += 256) xd_s[i] = Xi_dense[n0 * ND + i];
    if (t < HIDN) { s1_s[t] = 0.f; q1_s[t] = 0.f; }
    __syncthreads();

    // ---- phase A: embeddings. thread (r,q): row r (16/block), emb-lane q ----
    const int r = t >> 4;
    const int q = t & 15;
    const int n = n0 + r;

    float first_p = 0.f, s_q = 0.f, ssq_q = 0.f;
    float* drow = &deep_s[r * DDIM];

    #pragma unroll
    for (int f = 0; f < ND; ++f) {
        float xv = xv_s[r * NF + f];
        float xd = xd_s[r * ND + f];
        float v1 = fmaf(xd, W1d[f * EMBD + q], b1d[f * EMBD + q]) * xv;
        float v2 = fmaf(xd, W2d[f * EMBD + q], b2d[f * EMBD + q]) * xv;
        first_p += v1;
        s_q += v2;
        ssq_q = fmaf(v2, v2, ssq_q);
        drow[f * EMBD + q] = v2;
    }
    #pragma unroll 4
    for (int fs = 0; fs < NS; ++fs) {
        float xv = xv_s[r * NF + ND + fs];
        int   ix = xs_s[r * NS + fs];
        int  off = (fs * VOCABN + ix) * EMBD + q;
        float v1 = T1[off] * xv;
        float v2 = T2[off] * xv;
        first_p += v1;
        s_q += v2;
        ssq_q = fmaf(v2, v2, ssq_q);
        drow[(ND + fs) * EMBD + q] = v2;
    }
    // per-row scalar: first_sum contribution + FM contribution for this e-lane
    float contrib = first_p + 0.5f * (s_q * s_q - ssq_q);
    #pragma unroll
    for (int m = 1; m < 16; m <<= 1) contrib += __shfl_xor(contrib, m, 64);
    if (q == 0) base[n] = contrib + bias[n];
    __syncthreads();

    // ---- phase B: y1[r][2c], y1[r][2c+1] = deep[r,:] @ Wl1 + bl1 ----
    const int c = q;                       // 0..15, j-pair (2c, 2c+1)
    float a0 = bl1[2 * c], a1 = bl1[2 * c + 1];
    const float2* __restrict__ Wv = (const float2*)Wl1;  // [624][16] float2
    #pragma unroll 4
    for (int d = 0; d < DDIM; d += 4) {
        float4 av = *(const float4*)(drow + d);      // LDS b128, broadcast
        float2 w0 = Wv[(d + 0) * 16 + c];
        float2 w1 = Wv[(d + 1) * 16 + c];
        float2 w2 = Wv[(d + 2) * 16 + c];
        float2 w3 = Wv[(d + 3) * 16 + c];
        a0 = fmaf(av.x, w0.x, a0); a1 = fmaf(av.x, w0.y, a1);
        a0 = fmaf(av.y, w1.x, a0); a1 = fmaf(av.y, w1.y, a1);
        a0 = fmaf(av.z, w2.x, a0); a1 = fmaf(av.z, w2.y, a1);
        a0 = fmaf(av.w, w3.x, a0); a1 = fmaf(av.w, w3.y, a1);
    }
    ((float2*)(y1 + (size_t)n * HIDN))[c] = make_float2(a0, a1);

    // BN1 stats: reduce over the wave's 4 rows, then LDS, then global atomics
    float p0 = a0, p1 = a1, p2 = a0 * a0, p3 = a1 * a1;
    p0 += __shfl_xor(p0, 16, 64); p1 += __shfl_xor(p1, 16, 64);
    p2 += __shfl_xor(p2, 16, 64); p3 += __shfl_xor(p3, 16, 64);
    p0 += __shfl_xor(p0, 32, 64); p1 += __shfl_xor(p1, 32, 64);
    p2 += __shfl_xor(p2, 32, 64); p3 += __shfl_xor(p3, 32, 64);
    if ((t & 48) == 0) {
        atomicAdd(&s1_s[2 * c],     p0);
        atomicAdd(&s1_s[2 * c + 1], p1);
        atomicAdd(&q1_s[2 * c],     p2);
        atomicAdd(&q1_s[2 * c + 1], p3);
    }
    __syncthreads();
    if (t < HIDN) { atomicAdd(&S1[t], s1_s[t]); atomicAdd(&Q1[t], q1_s[t]); }
}

// ---------------------------------------------------------------------------
// K2: fold BN1 affine into the second layer:  V[k][j]=alpha_k*Wl2[k][j],
//     c[j] = sum_k beta_k*Wl2[k][j] + bl2[j]
// ---------------------------------------------------------------------------
__global__ void k2_bn1(const float* __restrict__ S1, const float* __restrict__ Q1,
                       const float* __restrict__ g1, const float* __restrict__ be1,
                       const float* __restrict__ Wl2, const float* __restrict__ bl2,
                       float* __restrict__ V, float* __restrict__ cvec)
{
    const int j = threadIdx.x;            // 32 threads
    __shared__ float alpha[HIDN], beta[HIDN];
    float m   = S1[j] * (1.f / NROWS);
    float var = Q1[j] * (1.f / NROWS) - m * m;
    float rs  = rsqrtf(var + EPSF);
    float a   = g1[j] * rs;
    alpha[j] = a;
    beta[j]  = be1[j] - a * m;
    __syncthreads();
    float c = bl2[j];
    for (int k = 0; k < HIDN; ++k) {
        float w = Wl2[k * HIDN + j];
        V[k * HIDN + j] = alpha[k] * w;
        c = fmaf(beta[k], w, c);
    }
    cvec[j] = c;
}

// ---------------------------------------------------------------------------
// K3: batch moments of y2 = y1@V + c (y2 never stored)
// ---------------------------------------------------------------------------
__global__ __launch_bounds__(256) void k3_stats2(
    const float* __restrict__ y1, const float* __restrict__ V,
    const float* __restrict__ cvec,
    float* __restrict__ S2, float* __restrict__ Q2)
{
    __shared__ float Vs[HIDN * HIDN];
    __shared__ float cs[HIDN];
    __shared__ float ys[32 * HIDN];
    __shared__ float s2_s[HIDN], q2_s[HIDN];
    const int t = threadIdx.x;
    const size_t n0 = (size_t)blockIdx.x * 32;
    for (int i = t; i < HIDN * HIDN; i += 256) Vs[i] = V[i];
    for (int i = t; i < 32 * HIDN; i += 256) ys[i] = y1[n0 * HIDN + i];
    if (t < HIDN) { cs[t] = cvec[t]; s2_s[t] = 0.f; q2_s[t] = 0.f; }
    __syncthreads();
    const int j = t & 31, rr = t >> 5;
    float ps = 0.f, pq = 0.f;
    #pragma unroll
    for (int g = 0; g < 4; ++g) {
        int r = g * 8 + rr;
        float acc = cs[j];
        #pragma unroll
        for (int k = 0; k < HIDN; ++k) acc = fmaf(ys[r * HIDN + k], Vs[k * HIDN + j], acc);
        ps += acc;
        pq = fmaf(acc, acc, pq);
    }
    ps += __shfl_xor(ps, 32, 64);
    pq += __shfl_xor(pq, 32, 64);
    if ((t & 32) == 0) { atomicAdd(&s2_s[j], ps); atomicAdd(&q2_s[j], pq); }
    __syncthreads();
    if (t < HIDN) { atomicAdd(&S2[t], s2_s[t]); atomicAdd(&Q2[t], q2_s[t]); }
}

// ---------------------------------------------------------------------------
// K4: collapse BN2 + Wl2 path + final h.sum into w[32] and scalar C:
//   total[n] = base[n] + y1[n,:].w + C
// ---------------------------------------------------------------------------
__global__ void k4_bn2(const float* __restrict__ S2, const float* __restrict__ Q2,
                       const float* __restrict__ g2, const float* __restrict__ be2,
                       const float* __restrict__ V, const float* __restrict__ cvec,
                       float* __restrict__ wvec, float* __restrict__ Cc)
{
    const int k = threadIdx.x;            // 32 threads
    __shared__ float gamma[HIDN], cpart[HIDN];
    float m   = S2[k] * (1.f / NROWS);
    float var = Q2[k] * (1.f / NROWS) - m * m;
    float rs  = rsqrtf(var + EPSF);
    float g   = g2[k] * rs;
    gamma[k] = g;
    cpart[k] = be2[k] - g * m + g * cvec[k];
    __syncthreads();
    float w = 0.f;
    for (int j = 0; j < HIDN; ++j) w = fmaf(gamma[j], V[k * HIDN + j], w);
    wvec[k] = w;
    if (k == 0) {
        float C = 0.f;
        for (int j = 0; j < HIDN; ++j) C += cpart[j];
        Cc[0] = C;
    }
}

// ---------------------------------------------------------------------------
// K5: final: out[n] = base[n] + dot(y1[n,:], w) + C
// ---------------------------------------------------------------------------
__global__ __launch_bounds__(256) void k5_final(
    const float* __restrict__ y1, const float* __restrict__ base,
    const float* __restrict__ wvec, const float* __restrict__ Cc,
    float* __restrict__ out)
{
    __shared__ float ws_s[HIDN];
    __shared__ float Cs;
    const int t = threadIdx.x;
    if (t < HIDN) ws_s[t] = wvec[t];
    if (t == 0) Cs = Cc[0];
    __syncthreads();
    const size_t n = (size_t)blockIdx.x * 256 + t;
    const float4* yv = (const float4*)(y1 + n * HIDN);
    float acc = base[n] + Cs;
    #pragma unroll
    for (int kk = 0; kk < 8; ++kk) {
        float4 v = yv[kk];
        acc = fmaf(v.x, ws_s[4 * kk + 0], acc);
        acc = fmaf(v.y, ws_s[4 * kk + 1], acc);
        acc = fmaf(v.z, ws_s[4 * kk + 2], acc);
        acc = fmaf(v.w, ws_s[4 * kk + 3], acc);
    }
    out[n] = acc;
}

extern "C" void kernel_launch(void* const* d_in, const int* in_sizes, int n_in,
                              void* d_out, int out_size, void* d_ws, size_t ws_size,
                              hipStream_t stream)
{
    const float* Xi_dense = (const float*)d_in[0];
    const int*   Xi_sparse= (const int*)  d_in[1];
    const float* Xv       = (const float*)d_in[2];
    const float* bias     = (const float*)d_in[3];
    const float* W1d      = (const float*)d_in[4];
    const float* b1d      = (const float*)d_in[5];
    const float* T1       = (const float*)d_in[6];
    const float* W2d      = (const float*)d_in[7];
    const float* b2d      = (const float*)d_in[8];
    const float* T2       = (const float*)d_in[9];
    const float* Wl1      = (const float*)d_in[10];
    const float* bl1      = (const float*)d_in[11];
    const float* g1       = (const float*)d_in[12];
    const float* be1      = (const float*)d_in[13];
    const float* Wl2      = (const float*)d_in[14];
    const float* bl2      = (const float*)d_in[15];
    const float* g2       = (const float*)d_in[16];
    const float* be2      = (const float*)d_in[17];
    float* out = (float*)d_out;

    // workspace layout (floats):
    // [0:32) S1 | [32:64) Q1 | [64:96) S2 | [96:128) Q2   <- zeroed each launch
    // [128:1152) V | [1152:1184) cvec | [1184:1216) wvec | [1216:1217) C
    // [2048 : 2048+N) base | [2048+N : 2048+N+32N) y1
    float* ws   = (float*)d_ws;
    float* S1   = ws + 0;
    float* Q1   = ws + 32;
    float* S2   = ws + 64;
    float* Q2   = ws + 96;
    float* V    = ws + 128;
    float* cvec = ws + 1152;
    float* wvec = ws + 1184;
    float* Cc   = ws + 1216;
    float* base = ws + 2048;
    float* y1   = ws + 2048 + NROWS;

    hipMemsetAsync(ws, 0, 128 * sizeof(float), stream);

    k1_embed<<<NROWS / 16, 256, 0, stream>>>(Xi_dense, Xi_sparse, Xv, bias,
                                             W1d, b1d, T1, W2d, b2d, T2,
                                             Wl1, bl1, base, y1, S1, Q1);
    k2_bn1<<<1, 32, 0, stream>>>(S1, Q1, g1, be1, Wl2, bl2, V, cvec);
    k3_stats2<<<NROWS / 32, 256, 0, stream>>>(y1, V, cvec, S2, Q2);
    k4_bn2<<<1, 32, 0, stream>>>(S2, Q2, g2, be2, V, cvec, wvec, Cc);
    k5_final<<<NROWS / 256, 256, 0, stream>>>(y1, base, wvec, Cc, out);
}

// Round 2
// 941.716 us; speedup vs baseline: 1.1719x; 1.1719x over previous
//
#include <hip/hip_runtime.h>

#define NROWS  131072
#define ND     13
#define NS     26
#define NF     39
#define EMBD   16
#define DDIM   624      // 39*16
#define HIDN   32
#define VOCABN 100000
#define EPSF   1e-5f
#define NREP   64       // replica slots for global stat accumulation

// ---------------------------------------------------------------------------
// K1: per 16-row block.
// Gather layout: 16 lanes/row; lane q owns emb-part p=q&3 (positions 4p..4p+3)
// and fields f = (q>>2) + 4i  -> every load is a float4; 4 lanes cover one
// 64B table line; 12-14 independent loads per thread for MLP.
// ---------------------------------------------------------------------------
__global__ __launch_bounds__(256) void k1_embed(
    const float* __restrict__ Xi_dense, const int* __restrict__ Xi_sparse,
    const float* __restrict__ Xv, const float* __restrict__ bias,
    const float* __restrict__ W1d, const float* __restrict__ b1d,
    const float* __restrict__ T1,
    const float* __restrict__ W2d, const float* __restrict__ b2d,
    const float* __restrict__ T2,
    const float* __restrict__ Wl1, const float* __restrict__ bl1,
    float* __restrict__ base, float* __restrict__ y1,
    float* __restrict__ S1rep, float* __restrict__ Q1rep)
{
    __shared__ float4 deep4[16 * 156];    // 16 rows x 624 floats, 39.9 KB
    __shared__ float  xv_s[16 * NF];
    __shared__ int    xs_s[16 * NS];
    __shared__ float  xd_s[16 * ND];
    __shared__ float  sden[16][16];       // dense part of s-vector
    __shared__ float  s1_s[HIDN], q1_s[HIDN];

    const int t  = threadIdx.x;
    const int n0 = blockIdx.x * 16;

    for (int i = t; i < 16 * NF; i += 256) xv_s[i] = Xv[n0 * NF + i];
    for (int i = t; i < 16 * NS; i += 256) xs_s[i] = Xi_sparse[n0 * NS + i];
    for (int i = t; i < 16 * ND; i += 256) xd_s[i] = Xi_dense[n0 * ND + i];
    if (t < HIDN) { s1_s[t] = 0.f; q1_s[t] = 0.f; }
    __syncthreads();

    const int r = t >> 4;
    const int q = t & 15;
    const int n = n0 + r;
    float* drow = (float*)deep4 + r * DDIM;

    // ---- dense fields: lane q handles emb position q for all 13 fields ----
    float first_p = 0.f, ssq_p = 0.f, sq = 0.f;
    #pragma unroll
    for (int f = 0; f < ND; ++f) {
        float xv = xv_s[r * NF + f];
        float xd = xd_s[r * ND + f];
        float v1 = fmaf(xd, W1d[f * EMBD + q], b1d[f * EMBD + q]) * xv;
        float v2 = fmaf(xd, W2d[f * EMBD + q], b2d[f * EMBD + q]) * xv;
        first_p += v1;
        sq += v2;
        ssq_p = fmaf(v2, v2, ssq_p);
        drow[f * EMBD + q] = v2;
    }
    sden[r][q] = sq;

    // ---- sparse fields: float4 gather, high MLP ----
    const int pp = q & 3;        // emb-part (positions 4pp..4pp+3)
    const int p4 = pp * 4;
    const int fb = q >> 2;       // field class mod 4
    float4 s4 = make_float4(0.f, 0.f, 0.f, 0.f);

    auto body = [&](int fs) {
        int   ix = xs_s[r * NS + fs];
        float xv = xv_s[r * NF + ND + fs];
        int  off = (fs * VOCABN + ix) * EMBD + p4;
        float4 a = *(const float4*)(T1 + off);
        float4 b = *(const float4*)(T2 + off);
        first_p += xv * ((a.x + a.y) + (a.z + a.w));
        float4 v2 = make_float4(b.x * xv, b.y * xv, b.z * xv, b.w * xv);
        s4.x += v2.x; s4.y += v2.y; s4.z += v2.z; s4.w += v2.w;
        ssq_p = fmaf(v2.x, v2.x, ssq_p);
        ssq_p = fmaf(v2.y, v2.y, ssq_p);
        ssq_p = fmaf(v2.z, v2.z, ssq_p);
        ssq_p = fmaf(v2.w, v2.w, ssq_p);
        deep4[r * 156 + (ND + fs) * 4 + pp] = v2;
    };
    #pragma unroll
    for (int i = 0; i < 6; ++i) body(fb + 4 * i);
    if (q < 8) body(fb + 24);    // fields 24,25 (classes 0,1 get a 7th chunk)

    // sum s4 over the 4 lanes sharing part pp (q, q^4, q^8, q^12: same row)
    s4.x += __shfl_xor(s4.x, 4, 64);  s4.y += __shfl_xor(s4.y, 4, 64);
    s4.z += __shfl_xor(s4.z, 4, 64);  s4.w += __shfl_xor(s4.w, 4, 64);
    s4.x += __shfl_xor(s4.x, 8, 64);  s4.y += __shfl_xor(s4.y, 8, 64);
    s4.z += __shfl_xor(s4.z, 8, 64);  s4.w += __shfl_xor(s4.w, 8, 64);

    __syncthreads();   // publish sden + deep4 (also covers phase B reads)

    float4 sd = *(const float4*)(&sden[r][p4]);
    float sx = s4.x + sd.x, sy = s4.y + sd.y, sz = s4.z + sd.z, sw = s4.w + sd.w;
    float sdot = sx * sx + sy * sy + sz * sz + sw * sw;
    float contrib = first_p - 0.5f * ssq_p + ((q < 4) ? 0.5f * sdot : 0.f);
    contrib += __shfl_xor(contrib, 1, 64);
    contrib += __shfl_xor(contrib, 2, 64);
    contrib += __shfl_xor(contrib, 4, 64);
    contrib += __shfl_xor(contrib, 8, 64);
    if (q == 0) base[n] = contrib + bias[n];

    // ---- phase B: y1[r][4c..4c+3], d-range split across h=q&1 ----
    const int c = q >> 1;        // 0..7: j-quad
    const int h = q & 1;         // d-half
    const float4* __restrict__ Wv4 = (const float4*)Wl1;    // [624][8] float4
    const float4* arow = deep4 + r * 156 + h * 78;
    float4 acc = make_float4(0.f, 0.f, 0.f, 0.f);
    #pragma unroll 2
    for (int dd = 0; dd < 312; dd += 4) {
        float4 a = arow[dd >> 2];
        int dbase = (h * 312 + dd) * 8 + c;
        float4 w0 = Wv4[dbase];
        float4 w1 = Wv4[dbase + 8];
        float4 w2 = Wv4[dbase + 16];
        float4 w3 = Wv4[dbase + 24];
        acc.x = fmaf(a.x, w0.x, acc.x); acc.y = fmaf(a.x, w0.y, acc.y);
        acc.z = fmaf(a.x, w0.z, acc.z); acc.w = fmaf(a.x, w0.w, acc.w);
        acc.x = fmaf(a.y, w1.x, acc.x); acc.y = fmaf(a.y, w1.y, acc.y);
        acc.z = fmaf(a.y, w1.z, acc.z); acc.w = fmaf(a.y, w1.w, acc.w);
        acc.x = fmaf(a.z, w2.x, acc.x); acc.y = fmaf(a.z, w2.y, acc.y);
        acc.z = fmaf(a.z, w2.z, acc.z); acc.w = fmaf(a.z, w2.w, acc.w);
        acc.x = fmaf(a.w, w3.x, acc.x); acc.y = fmaf(a.w, w3.y, acc.y);
        acc.z = fmaf(a.w, w3.z, acc.z); acc.w = fmaf(a.w, w3.w, acc.w);
    }
    // combine the two d-halves (lanes t, t^1)
    acc.x += __shfl_xor(acc.x, 1, 64);
    acc.y += __shfl_xor(acc.y, 1, 64);
    acc.z += __shfl_xor(acc.z, 1, 64);
    acc.w += __shfl_xor(acc.w, 1, 64);
    if (h == 0) {
        float4 bv = ((const float4*)bl1)[c];
        acc.x += bv.x; acc.y += bv.y; acc.z += bv.z; acc.w += bv.w;
        ((float4*)(y1 + (size_t)n * HIDN))[c] = acc;
    }
    // BN1 stats: rows reduce via xor 16/32 (h-parity preserved by partners)
    float sx_ = acc.x, sy_ = acc.y, sz_ = acc.z, sw_ = acc.w;
    float qx_ = acc.x * acc.x, qy_ = acc.y * acc.y;
    float qz_ = acc.z * acc.z, qw_ = acc.w * acc.w;
    sx_ += __shfl_xor(sx_, 16, 64); sy_ += __shfl_xor(sy_, 16, 64);
    sz_ += __shfl_xor(sz_, 16, 64); sw_ += __shfl_xor(sw_, 16, 64);
    qx_ += __shfl_xor(qx_, 16, 64); qy_ += __shfl_xor(qy_, 16, 64);
    qz_ += __shfl_xor(qz_, 16, 64); qw_ += __shfl_xor(qw_, 16, 64);
    sx_ += __shfl_xor(sx_, 32, 64); sy_ += __shfl_xor(sy_, 32, 64);
    sz_ += __shfl_xor(sz_, 32, 64); sw_ += __shfl_xor(sw_, 32, 64);
    qx_ += __shfl_xor(qx_, 32, 64); qy_ += __shfl_xor(qy_, 32, 64);
    qz_ += __shfl_xor(qz_, 32, 64); qw_ += __shfl_xor(qw_, 32, 64);
    if ((t & 49) == 0) {          // h==0 && r==0: one lane per c
        atomicAdd(&s1_s[4 * c + 0], sx_); atomicAdd(&s1_s[4 * c + 1], sy_);
        atomicAdd(&s1_s[4 * c + 2], sz_); atomicAdd(&s1_s[4 * c + 3], sw_);
        atomicAdd(&q1_s[4 * c + 0], qx_); atomicAdd(&q1_s[4 * c + 1], qy_);
        atomicAdd(&q1_s[4 * c + 2], qz_); atomicAdd(&q1_s[4 * c + 3], qw_);
    }
    __syncthreads();
    if (t < HIDN) {
        int rep = blockIdx.x & (NREP - 1);
        atomicAdd(&S1rep[rep * HIDN + t], s1_s[t]);
        atomicAdd(&Q1rep[rep * HIDN + t], q1_s[t]);
    }
}

// ---------------------------------------------------------------------------
// K2: reduce S1/Q1 replicas, fold BN1 affine into layer 2:
//   V[k][j] = alpha_k*Wl2[k][j];  c[j] = sum_k beta_k*Wl2[k][j] + bl2[j]
// ---------------------------------------------------------------------------
__global__ void k2_bn1(const float* __restrict__ S1rep, const float* __restrict__ Q1rep,
                       const float* __restrict__ g1, const float* __restrict__ be1,
                       const float* __restrict__ Wl2, const float* __restrict__ bl2,
                       float* __restrict__ V, float* __restrict__ cvec)
{
    const int j = threadIdx.x;            // 32 threads
    __shared__ float alpha[HIDN], beta[HIDN];
    float s = 0.f, qq = 0.f;
    for (int rep = 0; rep < NREP; ++rep) {
        s  += S1rep[rep * HIDN + j];
        qq += Q1rep[rep * HIDN + j];
    }
    float m   = s * (1.f / NROWS);
    float var = qq * (1.f / NROWS) - m * m;
    float rs  = rsqrtf(var + EPSF);
    float a   = g1[j] * rs;
    alpha[j] = a;
    beta[j]  = be1[j] - a * m;
    __syncthreads();
    float c = bl2[j];
    for (int k = 0; k < HIDN; ++k) {
        float w = Wl2[k * HIDN + j];
        V[k * HIDN + j] = alpha[k] * w;
        c = fmaf(beta[k], w, c);
    }
    cvec[j] = c;
}

// ---------------------------------------------------------------------------
// K3: batch moments of y2 = y1@V + c (y2 never stored)
// ---------------------------------------------------------------------------
__global__ __launch_bounds__(256) void k3_stats2(
    const float* __restrict__ y1, const float* __restrict__ V,
    const float* __restrict__ cvec,
    float* __restrict__ S2rep, float* __restrict__ Q2rep)
{
    __shared__ float4 Vs4[256];           // V, 32x32
    __shared__ float4 ys4[256];           // 32 rows of y1
    __shared__ float  cs[HIDN], s2_s[HIDN], q2_s[HIDN];
    const int t = threadIdx.x;
    const size_t n0 = (size_t)blockIdx.x * 32;
    Vs4[t] = ((const float4*)V)[t];
    ys4[t] = ((const float4*)(y1 + n0 * HIDN))[t];
    if (t < HIDN) { cs[t] = cvec[t]; s2_s[t] = 0.f; q2_s[t] = 0.f; }
    __syncthreads();
    const int j = t & 31, rr = t >> 5;
    const float* Vf = (const float*)Vs4;
    float Vcol[HIDN];
    #pragma unroll
    for (int k = 0; k < HIDN; ++k) Vcol[k] = Vf[k * HIDN + j];
    float ps = 0.f, pq = 0.f;
    #pragma unroll
    for (int g = 0; g < 4; ++g) {
        int rrow = rr + 8 * g;
        float acc = cs[j];
        #pragma unroll
        for (int kk = 0; kk < 8; ++kk) {
            float4 a = ys4[rrow * 8 + kk];
            acc = fmaf(a.x, Vcol[4 * kk + 0], acc);
            acc = fmaf(a.y, Vcol[4 * kk + 1], acc);
            acc = fmaf(a.z, Vcol[4 * kk + 2], acc);
            acc = fmaf(a.w, Vcol[4 * kk + 3], acc);
        }
        ps += acc;
        pq = fmaf(acc, acc, pq);
    }
    ps += __shfl_xor(ps, 32, 64);
    pq += __shfl_xor(pq, 32, 64);
    if ((t & 32) == 0) { atomicAdd(&s2_s[j], ps); atomicAdd(&q2_s[j], pq); }
    __syncthreads();
    if (t < HIDN) {
        int rep = blockIdx.x & (NREP - 1);
        atomicAdd(&S2rep[rep * HIDN + t], s2_s[t]);
        atomicAdd(&Q2rep[rep * HIDN + t], q2_s[t]);
    }
}

// ---------------------------------------------------------------------------
// K4: reduce S2/Q2 replicas, collapse BN2 + h.sum into w[32], scalar C
// ---------------------------------------------------------------------------
__global__ void k4_bn2(const float* __restrict__ S2rep, const float* __restrict__ Q2rep,
                       const float* __restrict__ g2, const float* __restrict__ be2,
                       const float* __restrict__ V, const float* __restrict__ cvec,
                       float* __restrict__ wvec, float* __restrict__ Cc)
{
    const int k = threadIdx.x;            // 32 threads
    __shared__ float gamma[HIDN], cpart[HIDN];
    float s = 0.f, qq = 0.f;
    for (int rep = 0; rep < NREP; ++rep) {
        s  += S2rep[rep * HIDN + k];
        qq += Q2rep[rep * HIDN + k];
    }
    float m   = s * (1.f / NROWS);
    float var = qq * (1.f / NROWS) - m * m;
    float rs  = rsqrtf(var + EPSF);
    float g   = g2[k] * rs;
    gamma[k] = g;
    cpart[k] = be2[k] - g * m + g * cvec[k];
    __syncthreads();
    float w = 0.f;
    for (int j = 0; j < HIDN; ++j) w = fmaf(gamma[j], V[k * HIDN + j], w);
    wvec[k] = w;
    if (k == 0) {
        float C = 0.f;
        for (int j = 0; j < HIDN; ++j) C += cpart[j];
        Cc[0] = C;
    }
}

// ---------------------------------------------------------------------------
// K5: out[n] = base[n] + dot(y1[n,:], w) + C
// ---------------------------------------------------------------------------
__global__ __launch_bounds__(256) void k5_final(
    const float* __restrict__ y1, const float* __restrict__ base,
    const float* __restrict__ wvec, const float* __restrict__ Cc,
    float* __restrict__ out)
{
    __shared__ float ws_s[HIDN];
    __shared__ float Cs;
    const int t = threadIdx.x;
    if (t < HIDN) ws_s[t] = wvec[t];
    if (t == 0) Cs = Cc[0];
    __syncthreads();
    const size_t n = (size_t)blockIdx.x * 256 + t;
    const float4* yv = (const float4*)(y1 + n * HIDN);
    float acc = base[n] + Cs;
    #pragma unroll
    for (int kk = 0; kk < 8; ++kk) {
        float4 v = yv[kk];
        acc = fmaf(v.x, ws_s[4 * kk + 0], acc);
        acc = fmaf(v.y, ws_s[4 * kk + 1], acc);
        acc = fmaf(v.z, ws_s[4 * kk + 2], acc);
        acc = fmaf(v.w, ws_s[4 * kk + 3], acc);
    }
    out[n] = acc;
}

extern "C" void kernel_launch(void* const* d_in, const int* in_sizes, int n_in,
                              void* d_out, int out_size, void* d_ws, size_t ws_size,
                              hipStream_t stream)
{
    const float* Xi_dense = (const float*)d_in[0];
    const int*   Xi_sparse= (const int*)  d_in[1];
    const float* Xv       = (const float*)d_in[2];
    const float* bias     = (const float*)d_in[3];
    const float* W1d      = (const float*)d_in[4];
    const float* b1d      = (const float*)d_in[5];
    const float* T1       = (const float*)d_in[6];
    const float* W2d      = (const float*)d_in[7];
    const float* b2d      = (const float*)d_in[8];
    const float* T2       = (const float*)d_in[9];
    const float* Wl1      = (const float*)d_in[10];
    const float* bl1      = (const float*)d_in[11];
    const float* g1       = (const float*)d_in[12];
    const float* be1      = (const float*)d_in[13];
    const float* Wl2      = (const float*)d_in[14];
    const float* bl2      = (const float*)d_in[15];
    const float* g2       = (const float*)d_in[16];
    const float* be2      = (const float*)d_in[17];
    float* out = (float*)d_out;

    // workspace layout (floats):
    // [0:2048) S1rep | [2048:4096) Q1rep | [4096:6144) S2rep | [6144:8192) Q2rep
    // [8192:9216) V | [9216:9248) cvec | [9248:9280) wvec | [9280] C
    // [9472 : 9472+N) base | [9472+N : +32N) y1
    float* ws    = (float*)d_ws;
    float* S1rep = ws + 0;
    float* Q1rep = ws + 2048;
    float* S2rep = ws + 4096;
    float* Q2rep = ws + 6144;
    float* V     = ws + 8192;
    float* cvec  = ws + 9216;
    float* wvec  = ws + 9248;
    float* Cc    = ws + 9280;
    float* base  = ws + 9472;
    float* y1    = ws + 9472 + NROWS;

    hipMemsetAsync(ws, 0, 4 * NREP * HIDN * sizeof(float), stream);

    k1_embed<<<NROWS / 16, 256, 0, stream>>>(Xi_dense, Xi_sparse, Xv, bias,
                                             W1d, b1d, T1, W2d, b2d, T2,
                                             Wl1, bl1, base, y1, S1rep, Q1rep);
    k2_bn1<<<1, 32, 0, stream>>>(S1rep, Q1rep, g1, be1, Wl2, bl2, V, cvec);
    k3_stats2<<<NROWS / 32, 256, 0, stream>>>(y1, V, cvec, S2rep, Q2rep);
    k4_bn2<<<1, 32, 0, stream>>>(S2rep, Q2rep, g2, be2, V, cvec, wvec, Cc);
    k5_final<<<NROWS / 256, 256, 0, stream>>>(y1, base, wvec, Cc, out);
}

// Round 3
// 930.443 us; speedup vs baseline: 1.1861x; 1.0121x over previous
//
#include <hip/hip_runtime.h>

#define NROWS  131072
#define ND     13
#define NS     26
#define NF     39
#define EMBD   16
#define DDIM   624      // 39*16
#define HIDN   32
#define VOCABN 100000
#define EPSF   1e-5f
#define NREP   64       // replica slots for global stat accumulation

// ---------------------------------------------------------------------------
// K1: per 16-row block.
//  - sparse gather: ALL 14 float4 loads issued back-to-back into registers
//    (A[7]/B[7]) before any use -> ~224B/lane in flight (latency hiding).
//    Lane q owns emb-part pp=q&3 and field classes fb=q>>2 (+4i); the i=6
//    chunk is a dummy (xv=0, field 0) for fb>=2 so all lanes issue uniformly.
//  - dense-field compute sits between issue and consume to overlap latency.
//  - base[n] = first.sum + fm2 + bias
//  - phase B: y1 = deep @ Wl1 + bl1 (deep staged in LDS)
//  - stats: S1 (column sums) and M = y1^T y1 (32x32, diag = Q1) via
//    per-block LDS tile + replicated global atomics. k3 is then algebraic.
// ---------------------------------------------------------------------------
__global__ __launch_bounds__(256, 3) void k1_embed(
    const float* __restrict__ Xi_dense, const int* __restrict__ Xi_sparse,
    const float* __restrict__ Xv, const float* __restrict__ bias,
    const float* __restrict__ W1d, const float* __restrict__ b1d,
    const float* __restrict__ T1,
    const float* __restrict__ W2d, const float* __restrict__ b2d,
    const float* __restrict__ T2,
    const float* __restrict__ Wl1, const float* __restrict__ bl1,
    float* __restrict__ base, float* __restrict__ y1,
    float* __restrict__ S1rep, float* __restrict__ Mrep)
{
    __shared__ float4 deep4[16 * 156];    // 39936 B
    __shared__ float  xv_s[16 * NF];
    __shared__ int    xs_s[16 * NS];
    __shared__ float  xd_s[16 * ND];
    __shared__ float  sden[16][16];
    __shared__ float  ys[16][HIDN];       // y1 tile for M accumulation

    const int t  = threadIdx.x;
    const int n0 = blockIdx.x * 16;

    for (int i = t; i < 16 * NF; i += 256) xv_s[i] = Xv[n0 * NF + i];
    for (int i = t; i < 16 * NS; i += 256) xs_s[i] = Xi_sparse[n0 * NS + i];
    for (int i = t; i < 16 * ND; i += 256) xd_s[i] = Xi_dense[n0 * ND + i];
    __syncthreads();

    const int r = t >> 4;
    const int q = t & 15;
    const int n = n0 + r;
    float* drow = (float*)deep4 + r * DDIM;

    const int pp = q & 3;        // emb-part (positions 4pp..4pp+3)
    const int p4 = pp * 4;
    const int fb = q >> 2;       // field class mod 4

    // ---- issue ALL sparse gathers first (14 independent float4 loads) ----
    float4 A[7], B[7];
    float  xvv[7];
    #pragma unroll
    for (int i = 0; i < 7; ++i) {
        int  fs    = fb + 4 * i;
        bool valid = (fs < NS);
        int  fse   = valid ? fs : 0;
        xvv[i] = valid ? xv_s[r * NF + ND + fse] : 0.f;
        int ix  = xs_s[r * NS + fse];
        int off = (fse * VOCABN + ix) * EMBD + p4;
        A[i] = *(const float4*)(T1 + off);
        B[i] = *(const float4*)(T2 + off);
    }

    // ---- dense fields (overlaps the gather latency) ----
    float first_p = 0.f, ssq_p = 0.f, sq = 0.f;
    #pragma unroll
    for (int f = 0; f < ND; ++f) {
        float xv = xv_s[r * NF + f];
        float xd = xd_s[r * ND + f];
        float v1 = fmaf(xd, W1d[f * EMBD + q], b1d[f * EMBD + q]) * xv;
        float v2 = fmaf(xd, W2d[f * EMBD + q], b2d[f * EMBD + q]) * xv;
        first_p += v1;
        sq += v2;
        ssq_p = fmaf(v2, v2, ssq_p);
        drow[f * EMBD + q] = v2;
    }
    sden[r][q] = sq;

    // ---- consume gathers ----
    float4 s4 = make_float4(0.f, 0.f, 0.f, 0.f);
    #pragma unroll
    for (int i = 0; i < 7; ++i) {
        float  xv = xvv[i];
        float4 a  = A[i];
        float4 b  = B[i];
        first_p = fmaf(xv, (a.x + a.y) + (a.z + a.w), first_p);
        float4 v2 = make_float4(b.x * xv, b.y * xv, b.z * xv, b.w * xv);
        s4.x += v2.x; s4.y += v2.y; s4.z += v2.z; s4.w += v2.w;
        ssq_p = fmaf(v2.x, v2.x, ssq_p);
        ssq_p = fmaf(v2.y, v2.y, ssq_p);
        ssq_p = fmaf(v2.z, v2.z, ssq_p);
        ssq_p = fmaf(v2.w, v2.w, ssq_p);
        int fs = fb + 4 * i;
        if (fs < NS) deep4[r * 156 + (ND + fs) * 4 + pp] = v2;
    }

    // sum s4 over the 4 lanes sharing part pp (q, q^4, q^8, q^12: same row)
    s4.x += __shfl_xor(s4.x, 4, 64);  s4.y += __shfl_xor(s4.y, 4, 64);
    s4.z += __shfl_xor(s4.z, 4, 64);  s4.w += __shfl_xor(s4.w, 4, 64);
    s4.x += __shfl_xor(s4.x, 8, 64);  s4.y += __shfl_xor(s4.y, 8, 64);
    s4.z += __shfl_xor(s4.z, 8, 64);  s4.w += __shfl_xor(s4.w, 8, 64);

    __syncthreads();   // publish sden + deep4

    float4 sd = *(const float4*)(&sden[r][p4]);
    float sx = s4.x + sd.x, sy = s4.y + sd.y, sz = s4.z + sd.z, sw = s4.w + sd.w;
    float sdot = sx * sx + sy * sy + sz * sz + sw * sw;
    float contrib = first_p - 0.5f * ssq_p + ((q < 4) ? 0.5f * sdot : 0.f);
    contrib += __shfl_xor(contrib, 1, 64);
    contrib += __shfl_xor(contrib, 2, 64);
    contrib += __shfl_xor(contrib, 4, 64);
    contrib += __shfl_xor(contrib, 8, 64);
    if (q == 0) base[n] = contrib + bias[n];

    // ---- phase B: y1[r][4c..4c+3], d-range split across h=q&1 ----
    const int c = q >> 1;        // 0..7: j-quad
    const int h = q & 1;         // d-half
    const float4* __restrict__ Wv4 = (const float4*)Wl1;    // [624][8] float4
    const float4* arow = deep4 + r * 156 + h * 78;
    float4 acc = make_float4(0.f, 0.f, 0.f, 0.f);
    #pragma unroll 2
    for (int dd = 0; dd < 312; dd += 4) {
        float4 a = arow[dd >> 2];
        int dbase = (h * 312 + dd) * 8 + c;
        float4 w0 = Wv4[dbase];
        float4 w1 = Wv4[dbase + 8];
        float4 w2 = Wv4[dbase + 16];
        float4 w3 = Wv4[dbase + 24];
        acc.x = fmaf(a.x, w0.x, acc.x); acc.y = fmaf(a.x, w0.y, acc.y);
        acc.z = fmaf(a.x, w0.z, acc.z); acc.w = fmaf(a.x, w0.w, acc.w);
        acc.x = fmaf(a.y, w1.x, acc.x); acc.y = fmaf(a.y, w1.y, acc.y);
        acc.z = fmaf(a.y, w1.z, acc.z); acc.w = fmaf(a.y, w1.w, acc.w);
        acc.x = fmaf(a.z, w2.x, acc.x); acc.y = fmaf(a.z, w2.y, acc.y);
        acc.z = fmaf(a.z, w2.z, acc.z); acc.w = fmaf(a.z, w2.w, acc.w);
        acc.x = fmaf(a.w, w3.x, acc.x); acc.y = fmaf(a.w, w3.y, acc.y);
        acc.z = fmaf(a.w, w3.z, acc.z); acc.w = fmaf(a.w, w3.w, acc.w);
    }
    // combine the two d-halves (lanes t, t^1)
    acc.x += __shfl_xor(acc.x, 1, 64);
    acc.y += __shfl_xor(acc.y, 1, 64);
    acc.z += __shfl_xor(acc.z, 1, 64);
    acc.w += __shfl_xor(acc.w, 1, 64);
    if (h == 0) {
        float4 bv = ((const float4*)bl1)[c];
        acc.x += bv.x; acc.y += bv.y; acc.z += bv.z; acc.w += bv.w;
        ((float4*)(y1 + (size_t)n * HIDN))[c] = acc;
        *(float4*)&ys[r][4 * c] = acc;
    }
    __syncthreads();   // publish ys

    // ---- stats: S1 (t<32) and M = ys^T ys (all 256 threads) ----
    const int rep = blockIdx.x & (NREP - 1);
    if (t < HIDN) {
        float s = 0.f;
        #pragma unroll
        for (int rr = 0; rr < 16; ++rr) s += ys[rr][t];
        atomicAdd(&S1rep[rep * HIDN + t], s);
    }
    {
        const int j1 = t >> 3;           // 0..31
        const int qd = t & 7;            // j2-quad 0..7
        float4 mp = make_float4(0.f, 0.f, 0.f, 0.f);
        #pragma unroll
        for (int rr = 0; rr < 16; ++rr) {
            float  a1 = ys[rr][j1];
            float4 b4 = *(const float4*)&ys[rr][qd * 4];
            mp.x = fmaf(a1, b4.x, mp.x);
            mp.y = fmaf(a1, b4.y, mp.y);
            mp.z = fmaf(a1, b4.z, mp.z);
            mp.w = fmaf(a1, b4.w, mp.w);
        }
        float* Md = &Mrep[rep * 1024 + t * 4];
        atomicAdd(Md + 0, mp.x);
        atomicAdd(Md + 1, mp.y);
        atomicAdd(Md + 2, mp.z);
        atomicAdd(Md + 3, mp.w);
    }
}

// ---------------------------------------------------------------------------
// K2: reduce S1/M replicas; BN1 fold; S2/Q2 closed-form from (S1, M);
//     BN2 fold; emit w[32], C.   y2 moments:  S2 = S1.V + N c,
//     Q2_j = V_j^T M V_j + 2 c_j (S1.V_j) + N c_j^2.
// ---------------------------------------------------------------------------
__global__ void k2_post(const float* __restrict__ S1rep, const float* __restrict__ Mrep,
                        const float* __restrict__ g1, const float* __restrict__ be1,
                        const float* __restrict__ Wl2, const float* __restrict__ bl2,
                        const float* __restrict__ g2, const float* __restrict__ be2,
                        float* __restrict__ wvec, float* __restrict__ Cc)
{
    __shared__ float Ms[1024], Vs[1024];
    __shared__ float S1s[HIDN], alpha[HIDN], beta[HIDN], cv[HIDN];
    __shared__ float gam[HIDN], cpart[HIDN];
    __shared__ float qpart[8][HIDN];
    const int t = threadIdx.x;

    {   // reduce M replicas
        float4 a4 = make_float4(0.f, 0.f, 0.f, 0.f);
        for (int rep = 0; rep < NREP; ++rep) {
            float4 v = ((const float4*)(Mrep + rep * 1024))[t];
            a4.x += v.x; a4.y += v.y; a4.z += v.z; a4.w += v.w;
        }
        ((float4*)Ms)[t] = a4;
    }
    if (t < HIDN) {
        float s = 0.f;
        for (int rep = 0; rep < NREP; ++rep) s += S1rep[rep * HIDN + t];
        S1s[t] = s;
    }
    __syncthreads();
    if (t < HIDN) {
        float m   = S1s[t] * (1.f / NROWS);
        float var = Ms[t * HIDN + t] * (1.f / NROWS) - m * m;
        float a   = g1[t] * rsqrtf(var + EPSF);
        alpha[t] = a;
        beta[t]  = be1[t] - a * m;
    }
    __syncthreads();
    for (int i = 0; i < 4; ++i) {
        int idx = t + 256 * i;
        Vs[idx] = alpha[idx >> 5] * Wl2[idx];
    }
    if (t < HIDN) {
        float c = bl2[t];
        for (int k = 0; k < HIDN; ++k) c = fmaf(beta[k], Wl2[k * HIDN + t], c);
        cv[t] = c;
    }
    __syncthreads();
    {   // quadratic form V_j^T M V_j, split over 8 k-groups
        const int j = t & 31, kg = t >> 5;
        float qp = 0.f;
        for (int kk = 0; kk < 4; ++kk) {
            int k = kg * 4 + kk;
            float u = 0.f;
            #pragma unroll
            for (int l = 0; l < HIDN; ++l) u = fmaf(Ms[k * HIDN + l], Vs[l * HIDN + j], u);
            qp = fmaf(Vs[k * HIDN + j], u, qp);
        }
        qpart[kg][j] = qp;
    }
    __syncthreads();
    if (t < HIDN) {
        float vmv = 0.f;
        #pragma unroll
        for (int g = 0; g < 8; ++g) vmv += qpart[g][t];
        float sv = 0.f;
        #pragma unroll
        for (int k = 0; k < HIDN; ++k) sv = fmaf(S1s[k], Vs[k * HIDN + t], sv);
        float S2 = sv + (float)NROWS * cv[t];
        float Q2 = vmv + 2.f * cv[t] * sv + (float)NROWS * cv[t] * cv[t];
        float m2 = S2 * (1.f / NROWS);
        float v2 = Q2 * (1.f / NROWS) - m2 * m2;
        float g  = g2[t] * rsqrtf(v2 + EPSF);
        gam[t]   = g;
        cpart[t] = g * (cv[t] - m2) + be2[t];
    }
    __syncthreads();
    if (t < HIDN) {
        float w = 0.f;
        #pragma unroll
        for (int j = 0; j < HIDN; ++j) w = fmaf(gam[j], Vs[t * HIDN + j], w);
        wvec[t] = w;
    }
    if (t == 0) {
        float C = 0.f;
        #pragma unroll
        for (int j = 0; j < HIDN; ++j) C += cpart[j];
        Cc[0] = C;
    }
}

// ---------------------------------------------------------------------------
// K5: out[n] = base[n] + dot(y1[n,:], w) + C
// ---------------------------------------------------------------------------
__global__ __launch_bounds__(256) void k5_final(
    const float* __restrict__ y1, const float* __restrict__ base,
    const float* __restrict__ wvec, const float* __restrict__ Cc,
    float* __restrict__ out)
{
    __shared__ float ws_s[HIDN];
    __shared__ float Cs;
    const int t = threadIdx.x;
    if (t < HIDN) ws_s[t] = wvec[t];
    if (t == 0) Cs = Cc[0];
    __syncthreads();
    const size_t n = (size_t)blockIdx.x * 256 + t;
    const float4* yv = (const float4*)(y1 + n * HIDN);
    float acc = base[n] + Cs;
    #pragma unroll
    for (int kk = 0; kk < 8; ++kk) {
        float4 v = yv[kk];
        acc = fmaf(v.x, ws_s[4 * kk + 0], acc);
        acc = fmaf(v.y, ws_s[4 * kk + 1], acc);
        acc = fmaf(v.z, ws_s[4 * kk + 2], acc);
        acc = fmaf(v.w, ws_s[4 * kk + 3], acc);
    }
    out[n] = acc;
}

extern "C" void kernel_launch(void* const* d_in, const int* in_sizes, int n_in,
                              void* d_out, int out_size, void* d_ws, size_t ws_size,
                              hipStream_t stream)
{
    const float* Xi_dense = (const float*)d_in[0];
    const int*   Xi_sparse= (const int*)  d_in[1];
    const float* Xv       = (const float*)d_in[2];
    const float* bias     = (const float*)d_in[3];
    const float* W1d      = (const float*)d_in[4];
    const float* b1d      = (const float*)d_in[5];
    const float* T1       = (const float*)d_in[6];
    const float* W2d      = (const float*)d_in[7];
    const float* b2d      = (const float*)d_in[8];
    const float* T2       = (const float*)d_in[9];
    const float* Wl1      = (const float*)d_in[10];
    const float* bl1      = (const float*)d_in[11];
    const float* g1       = (const float*)d_in[12];
    const float* be1      = (const float*)d_in[13];
    const float* Wl2      = (const float*)d_in[14];
    const float* bl2      = (const float*)d_in[15];
    const float* g2       = (const float*)d_in[16];
    const float* be2      = (const float*)d_in[17];
    float* out = (float*)d_out;

    // workspace layout (floats):
    // [0:2048)        S1rep  (64 x 32)
    // [2048:67584)    Mrep   (64 x 1024)
    // [67584:67616)   wvec
    // [67616]         C
    // [67840:+N)      base
    // [198912:+32N)   y1
    float* ws    = (float*)d_ws;
    float* S1rep = ws + 0;
    float* Mrep  = ws + 2048;
    float* wvec  = ws + 67584;
    float* Cc    = ws + 67616;
    float* base  = ws + 67840;
    float* y1    = ws + 198912;

    hipMemsetAsync(ws, 0, 67584 * sizeof(float), stream);

    k1_embed<<<NROWS / 16, 256, 0, stream>>>(Xi_dense, Xi_sparse, Xv, bias,
                                             W1d, b1d, T1, W2d, b2d, T2,
                                             Wl1, bl1, base, y1, S1rep, Mrep);
    k2_post<<<1, 256, 0, stream>>>(S1rep, Mrep, g1, be1, Wl2, bl2, g2, be2,
                                   wvec, Cc);
    k5_final<<<NROWS / 256, 256, 0, stream>>>(y1, base, wvec, Cc, out);
}